// Round 7
// baseline (1053.161 us; speedup 1.0000x reference)
//
#include <hip/hip_runtime.h>

#define N_VAR   100000
#define N_CSTR  50000
#define NEDGE   1000000
#define DIM     64

// Coarse buckets: 128 destination nodes each.
#define NBK_N 782           // ceil(100000/128)
#define NBK_C 391           // ceil(50000/128)
#define NBK_T 1173
#define NCHUNK 245          // ceil(1e6/4096) pass-A chunks per side

// ---------------------------------------------------------------------------
// Workspace layout (4-byte units), ~35.2 MB total:
//   0:         stats      256 (float)  -- zeroed
//   256:       bhist     1280 (int)    -- zeroed (node buckets 0..781, cstr at +782)
//   1536:      ab         256 (float)
//   1792:      gbase_n    800 (int)    [0..782], sentinel at 782
//   2592:      gbase_c    416 (int)    [0..391]
//   3008:      gcur_n     800 (int)
//   3808:      gcur_c     416 (int)
//   4224:      xcb    1600000 (bf16 normalized cstr feats, 50000x64 ushort)
//   1604224:   xnb    3200000 (bf16 normalized var  feats, 100000x64 ushort)
//   4804224:   ent_n  2000000 (int2: {src17|dlow7<<17, w})
//   6804224:   ent_c  2000000 (int2: {dst17|slow7<<17, w})
// agg rows live in d_out; out_k rewrites d_out in place.
// ---------------------------------------------------------------------------
#define OFF_STATS  0
#define OFF_BHIST  256
#define OFF_AB     1536
#define OFF_GBN    1792
#define OFF_GBC    2592
#define OFF_GCN    3008
#define OFF_GCC    3808
#define OFF_XCB    4224
#define OFF_XNB    1604224
#define OFF_ENT_N  4804224
#define OFF_ENT_C  6804224
#define WS_ZERO_N  1536

// ---------------------------------------------------------------------------
// BN column stats.
// ---------------------------------------------------------------------------
__global__ __launch_bounds__(256) void bn_stats_k(const float* __restrict__ x, int n,
                                                  float* __restrict__ stats) {
  int c = threadIdx.x & 63;
  int rg = threadIdx.x >> 6;
  float s = 0.f, q = 0.f;
  for (int r = blockIdx.x * 4 + rg; r < n; r += gridDim.x * 4) {
    float v = x[r * DIM + c];
    s += v;
    q += v * v;
  }
  __shared__ float sb[256], qb[256];
  sb[threadIdx.x] = s;
  qb[threadIdx.x] = q;
  __syncthreads();
  if (rg == 0) {
    s = sb[c] + sb[c + 64] + sb[c + 128] + sb[c + 192];
    q = qb[c] + qb[c + 64] + qb[c + 128] + qb[c + 192];
    atomicAdd(&stats[c], s);
    atomicAdd(&stats[64 + c], q);
  }
}

__global__ void bn_finalize_k(const float* __restrict__ stats,
                              const float* __restrict__ gn, const float* __restrict__ bn,
                              const float* __restrict__ gc, const float* __restrict__ bc,
                              float* __restrict__ ab) {
  int t = threadIdx.x;  // 0..127
  int c = t & 63;
  bool isC = t >= 64;
  const float* st = stats + (isC ? 128 : 0);
  float n = isC ? (float)N_CSTR : (float)N_VAR;
  float mean = st[c] / n;
  float var = st[64 + c] / n - mean * mean;
  float g = isC ? gc[c] : gn[c];
  float be = isC ? bc[c] : bn[c];
  float a = g * rsqrtf(var + 1e-5f);
  float b = be - mean * a;
  float* o = ab + (isC ? 128 : 0);
  o[c] = a;
  o[64 + c] = b;
}

// ---------------------------------------------------------------------------
// bf16 round-to-nearest-even.
// ---------------------------------------------------------------------------
__device__ __forceinline__ unsigned short f2bf(float f) {
  unsigned u = __float_as_uint(f);
  return (unsigned short)((u + 0x7FFFu + ((u >> 16) & 1u)) >> 16);
}

// Normalized bf16 feature table: dst[i] = bf16(src[i]*a[c]+b[c]).
__global__ __launch_bounds__(256) void cvt_k(const float4* __restrict__ src4,
                                             const float* __restrict__ ab,
                                             ushort4* __restrict__ dst, int n4) {
  int i4 = blockIdx.x * 256 + threadIdx.x;
  if (i4 >= n4) return;
  float4 v = src4[i4];
  int c0 = (i4 << 2) & 63;
  ushort4 o;
  o.x = f2bf(fmaf(v.x, ab[c0 + 0], ab[64 + c0 + 0]));
  o.y = f2bf(fmaf(v.y, ab[c0 + 1], ab[64 + c0 + 1]));
  o.z = f2bf(fmaf(v.z, ab[c0 + 2], ab[64 + c0 + 2]));
  o.w = f2bf(fmaf(v.w, ab[c0 + 3], ab[64 + c0 + 3]));
  dst[i4] = o;
}

// ---------------------------------------------------------------------------
// Coarse bucket histogram (both sides), LDS-aggregated.
// ---------------------------------------------------------------------------
__global__ __launch_bounds__(256) void bhist_k(const int4* __restrict__ es4,
                                               const int4* __restrict__ ed4,
                                               int* __restrict__ ws) {
  __shared__ int h[1280];
  for (int i = threadIdx.x; i < 1280; i += 256) h[i] = 0;
  __syncthreads();
  int stride = gridDim.x * 256;
  for (int i4 = blockIdx.x * 256 + threadIdx.x; i4 < NEDGE / 4; i4 += stride) {
    int4 d = ed4[i4];
    int4 s = es4[i4];
    atomicAdd(&h[d.x >> 7], 1);
    atomicAdd(&h[d.y >> 7], 1);
    atomicAdd(&h[d.z >> 7], 1);
    atomicAdd(&h[d.w >> 7], 1);
    atomicAdd(&h[NBK_N + (s.x >> 7)], 1);
    atomicAdd(&h[NBK_N + (s.y >> 7)], 1);
    atomicAdd(&h[NBK_N + (s.z >> 7)], 1);
    atomicAdd(&h[NBK_N + (s.w >> 7)], 1);
  }
  __syncthreads();
  int* gh = ws + OFF_BHIST;
  for (int i = threadIdx.x; i < NBK_T; i += 256)
    if (h[i]) atomicAdd(&gh[i], h[i]);
}

// ---------------------------------------------------------------------------
// Scan bucket counts -> gbase (+sentinel) and gcur, both segments. One WG.
// ---------------------------------------------------------------------------
__global__ __launch_bounds__(256) void bscan_k(int* __restrict__ ws) {
  __shared__ int sb[256];
  int t = threadIdx.x;
#pragma unroll
  for (int seg = 0; seg < 2; ++seg) {
    int nbk = seg ? NBK_C : NBK_N;
    const int* h = ws + OFF_BHIST + (seg ? NBK_N : 0);
    int* gb = ws + (seg ? OFF_GBC : OFF_GBN);
    int* gc = ws + (seg ? OFF_GCC : OFF_GCN);
    int base = t * 4;
    int c[4];
    int s0 = 0;
#pragma unroll
    for (int j = 0; j < 4; ++j) {
      c[j] = (base + j < nbk) ? h[base + j] : 0;
      s0 += c[j];
    }
    sb[t] = s0;
    __syncthreads();
    for (int d = 1; d < 256; d <<= 1) {
      int v = (t >= d) ? sb[t - d] : 0;
      __syncthreads();
      sb[t] += v;
      __syncthreads();
    }
    int ex = sb[t] - s0;
#pragma unroll
    for (int j = 0; j < 4; ++j) {
      if (base + j < nbk) {
        gb[base + j] = ex;
        gc[base + j] = ex;
      }
      ex += c[j];
    }
    if (t == 255) gb[nbk] = sb[255];  // sentinel = total (= NEDGE)
    __syncthreads();
  }
}

// ---------------------------------------------------------------------------
// Pass A: LDS multi-split of 4096-edge chunks into coarse buckets.
// Aggregated run allocation (<=782 atomics/WG) + run-contiguous flush.
// blockIdx.x < NCHUNK: node side (key=dst); else cstr side (key=src).
// ---------------------------------------------------------------------------
__global__ __launch_bounds__(256) void passA_k(const int4* __restrict__ es4,
                                               const int4* __restrict__ ed4,
                                               const float4* __restrict__ ea4,
                                               int* __restrict__ ws) {
  __shared__ int cntL[1024];
  __shared__ int runoffL[1024];
  __shared__ int gblL[1024];
  __shared__ int2 dataL[4096];
  __shared__ unsigned short bidL[4096];
  __shared__ int sbL[256];
  int side = (blockIdx.x >= NCHUNK);
  int chunk = side ? blockIdx.x - NCHUNK : blockIdx.x;
  int nbk = side ? NBK_C : NBK_N;
  int* gcur = ws + (side ? OFF_GCC : OFF_GCN);
  int2* ent = (int2*)(ws + (side ? OFF_ENT_C : OFF_ENT_N));
  int t = threadIdx.x;
  for (int i = t; i < 1024; i += 256) cntL[i] = 0;
  __syncthreads();
  int e0 = chunk * 4096;
  int base4 = chunk * 1024 + t * 4;
  int pk[16];
  int2 pay[16];
#pragma unroll
  for (int j = 0; j < 4; ++j) {
    int i4 = base4 + j;
    if (i4 < NEDGE / 4) {
      int4 sv = es4[i4];
      int4 dv = ed4[i4];
      float4 wv = ea4[i4];
      int ss[4] = {sv.x, sv.y, sv.z, sv.w};
      int dd[4] = {dv.x, dv.y, dv.z, dv.w};
      float ww[4] = {wv.x, wv.y, wv.z, wv.w};
#pragma unroll
      for (int k = 0; k < 4; ++k) {
        int s = ss[k], d = dd[k];
        int b = side ? (s >> 7) : (d >> 7);
        int pl = side ? (d | ((s & 127) << 17)) : (s | ((d & 127) << 17));
        int rank = atomicAdd(&cntL[b], 1);
        pk[j * 4 + k] = b * 4096 + rank;
        pay[j * 4 + k] = make_int2(pl, __float_as_int(ww[k]));
      }
    } else {
#pragma unroll
      for (int k = 0; k < 4; ++k) pk[j * 4 + k] = -1;
    }
  }
  __syncthreads();
  // exclusive scan of cntL[0..1024) -> runoffL
  int base = t * 4;
  int c[4];
  int s0 = 0;
#pragma unroll
  for (int j = 0; j < 4; ++j) {
    c[j] = cntL[base + j];
    s0 += c[j];
  }
  sbL[t] = s0;
  __syncthreads();
  for (int d = 1; d < 256; d <<= 1) {
    int v = (t >= d) ? sbL[t - d] : 0;
    __syncthreads();
    sbL[t] += v;
    __syncthreads();
  }
  int ex = sbL[t] - s0;
#pragma unroll
  for (int j = 0; j < 4; ++j) {
    runoffL[base + j] = ex;
    ex += c[j];
  }
  __syncthreads();
  // allocate global runs (aggregated atomics)
  for (int b = t; b < nbk; b += 256) {
    int cc = cntL[b];
    gblL[b] = cc ? atomicAdd(&gcur[b], cc) : 0;
  }
  __syncthreads();
  // place into LDS bins
#pragma unroll
  for (int j = 0; j < 16; ++j) {
    if (pk[j] >= 0) {
      int b = pk[j] >> 12;
      int slot = runoffL[b] + (pk[j] & 4095);
      dataL[slot] = pay[j];
      bidL[slot] = (unsigned short)b;
    }
  }
  __syncthreads();
  // run-contiguous flush
  int chunkN = min(4096, NEDGE - e0);
  for (int i = t; i < chunkN; i += 256) {
    int b = bidL[i];
    ent[gblL[b] + (i - runoffL[b])] = dataL[i];
  }
}

// ---------------------------------------------------------------------------
// Accumulate: one WG per coarse bucket (128 dst rows). LDS f32 accumulator;
// bf16 source-row gathers (128B/row); LDS atomic adds (2 lanes/bank = free).
// Writes mean-aggregated rows straight to agg (=d_out). Degrees counted here.
// ---------------------------------------------------------------------------
__global__ __launch_bounds__(256) void accum_k(int* __restrict__ ws,
                                               float* __restrict__ outbase) {
  __shared__ float acc[8192];  // 128 rows x 64 cols
  __shared__ int cnt[128];
  int x = blockIdx.x;
  int side = (x >= NBK_N);
  int bk = side ? x - NBK_N : x;
  const int* gbase = ws + (side ? OFF_GBC : OFF_GBN);
  const int2* ent = (const int2*)(ws + (side ? OFF_ENT_C : OFF_ENT_N));
  const unsigned short* tab =
      (const unsigned short*)(ws + (side ? OFF_XNB : OFF_XCB));
  float* agg = side ? outbase + (long)N_VAR * DIM : outbase;
  int n = side ? N_CSTR : N_VAR;
  int t = threadIdx.x, lane = t & 63, wv = t >> 6;
  for (int i = t; i < 8192; i += 256) acc[i] = 0.f;
  if (t < 128) cnt[t] = 0;
  __syncthreads();
  int beg = gbase[bk], end = gbase[bk + 1];
  for (int g = beg + wv * 4; g < end; g += 16) {
    int m = min(4, end - g);
    int2 E[4];
#pragma unroll
    for (int j = 0; j < 4; ++j)
      if (j < m) E[j] = ent[g + j];
    float V[4];
#pragma unroll
    for (int j = 0; j < 4; ++j)
      if (j < m) {
        int srcI = E[j].x & 0x1FFFF;
        unsigned short hv = tab[srcI * DIM + lane];
        V[j] = __uint_as_float(((unsigned)hv) << 16);
      }
#pragma unroll
    for (int j = 0; j < 4; ++j)
      if (j < m) {
        int dl = (E[j].x >> 17) & 127;
        float w = __int_as_float(E[j].y);
        atomicAdd(&acc[dl * DIM + lane], V[j] * w);
        if (lane == 0) atomicAdd(&cnt[dl], 1);
      }
  }
  __syncthreads();
  int rbase = bk * 128;
  for (int j = wv; j < 128; j += 4) {
    int r = rbase + j;
    if (r < n) agg[(long)r * DIM + lane] = acc[j * DIM + lane] / fmaxf((float)cnt[j], 1.f);
  }
}

// ---------------------------------------------------------------------------
// Output GEMM + epilogue in place; weights in registers, readlane broadcast.
// ---------------------------------------------------------------------------
__global__ __launch_bounds__(256) void out_k(
    const float* __restrict__ raw, const float* __restrict__ ab,
    const float* __restrict__ w_rel, const float* __restrict__ b_rel,
    const float* __restrict__ w_root, float* __restrict__ io, int n) {
  int lane = threadIdx.x & 63;
  float a = ab[lane], b = ab[64 + lane];
  float brel = b_rel[lane];
  float4 wr[16], wo[16];
#pragma unroll
  for (int i = 0; i < 16; ++i) {
    wr[i] = reinterpret_cast<const float4*>(w_rel + lane * DIM)[i];
    wo[i] = reinterpret_cast<const float4*>(w_root + lane * DIM)[i];
  }
  int wave = (blockIdx.x * blockDim.x + threadIdx.x) >> 6;
  int nw = (gridDim.x * blockDim.x) >> 6;
  for (int r = wave; r < n; r += nw) {
    float av = io[r * DIM + lane];
    float xv = fmaf(raw[r * DIM + lane], a, b);
    int avi = __float_as_int(av);
    int xvi = __float_as_int(xv);
    float acc0 = 0.f, acc1 = 0.f, acc2 = 0.f, acc3 = 0.f;
#pragma unroll
    for (int i = 0; i < 16; ++i) {
      acc0 = fmaf(__int_as_float(__builtin_amdgcn_readlane(avi, 4 * i + 0)), wr[i].x, acc0);
      acc1 = fmaf(__int_as_float(__builtin_amdgcn_readlane(avi, 4 * i + 1)), wr[i].y, acc1);
      acc2 = fmaf(__int_as_float(__builtin_amdgcn_readlane(avi, 4 * i + 2)), wr[i].z, acc2);
      acc3 = fmaf(__int_as_float(__builtin_amdgcn_readlane(avi, 4 * i + 3)), wr[i].w, acc3);
      acc0 = fmaf(__int_as_float(__builtin_amdgcn_readlane(xvi, 4 * i + 0)), wo[i].x, acc0);
      acc1 = fmaf(__int_as_float(__builtin_amdgcn_readlane(xvi, 4 * i + 1)), wo[i].y, acc1);
      acc2 = fmaf(__int_as_float(__builtin_amdgcn_readlane(xvi, 4 * i + 2)), wo[i].z, acc2);
      acc3 = fmaf(__int_as_float(__builtin_amdgcn_readlane(xvi, 4 * i + 3)), wo[i].w, acc3);
    }
    io[r * DIM + lane] = fmaxf((acc0 + acc1) + (acc2 + acc3) + brel + xv, 0.f);
  }
}

extern "C" void kernel_launch(void* const* d_in, const int* in_sizes, int n_in,
                              void* d_out, int out_size, void* d_ws, size_t ws_size,
                              hipStream_t stream) {
  const float* vf = (const float*)d_in[0];
  const float* cf = (const float*)d_in[1];
  const int* es = (const int*)d_in[2];
  const int* ed = (const int*)d_in[3];
  const float* ea = (const float*)d_in[4];
  const float* gn = (const float*)d_in[5];
  const float* bn = (const float*)d_in[6];
  const float* gc = (const float*)d_in[7];
  const float* bc = (const float*)d_in[8];
  const float* n_rel_w = (const float*)d_in[9];
  const float* n_rel_b = (const float*)d_in[10];
  const float* n_root_w = (const float*)d_in[11];
  const float* c_rel_w = (const float*)d_in[12];
  const float* c_rel_b = (const float*)d_in[13];
  const float* c_root_w = (const float*)d_in[14];
  float* out = (float*)d_out;
  int* wsi = (int*)d_ws;
  float* wsf = (float*)d_ws;

  float* stats = wsf + OFF_STATS;
  float* ab = wsf + OFF_AB;
  ushort4* xcb = (ushort4*)(wsi + OFF_XCB);
  ushort4* xnb = (ushort4*)(wsi + OFF_XNB);

  float* agg_node = out;
  float* agg_cstr = out + (long)N_VAR * DIM;

  hipMemsetAsync(d_ws, 0, (size_t)WS_ZERO_N * sizeof(int), stream);

  bn_stats_k<<<512, 256, 0, stream>>>(vf, N_VAR, stats);
  bn_stats_k<<<512, 256, 0, stream>>>(cf, N_CSTR, stats + 128);
  bn_finalize_k<<<1, 128, 0, stream>>>(stats, gn, bn, gc, bc, ab);

  // Normalized bf16 tables (sources for the two gather directions).
  cvt_k<<<(N_CSTR * DIM / 4 + 255) / 256, 256, 0, stream>>>((const float4*)cf, ab + 128,
                                                            xcb, N_CSTR * DIM / 4);
  cvt_k<<<(N_VAR * DIM / 4 + 255) / 256, 256, 0, stream>>>((const float4*)vf, ab,
                                                           xnb, N_VAR * DIM / 4);

  bhist_k<<<128, 256, 0, stream>>>((const int4*)es, (const int4*)ed, wsi);
  bscan_k<<<1, 256, 0, stream>>>(wsi);
  passA_k<<<2 * NCHUNK, 256, 0, stream>>>((const int4*)es, (const int4*)ed,
                                          (const float4*)ea, wsi);
  accum_k<<<NBK_T, 256, 0, stream>>>(wsi, out);

  out_k<<<1024, 256, 0, stream>>>(vf, ab, n_rel_w, n_rel_b, n_root_w, agg_node, N_VAR);
  out_k<<<512, 256, 0, stream>>>(cf, ab + 128, c_rel_w, c_rel_b, c_root_w, agg_cstr,
                                 N_CSTR);
}

// Round 8
// 375.560 us; speedup vs baseline: 2.8042x; 2.8042x over previous
//
#include <hip/hip_runtime.h>

#define N_VAR   100000
#define N_CSTR  50000
#define NEDGE   1000000
#define DIM     64

// Coarse buckets: 128 destination nodes each.
#define NBK_N 782           // ceil(100000/128)
#define NBK_C 391           // ceil(50000/128)
#define NBK_T 1173
#define NCHUNK 245          // ceil(1e6/4096) pass-A chunks per side

// ---------------------------------------------------------------------------
// Workspace layout (4-byte units), ~35.8 MB total:
//   0:         stats      256 (float)  -- zeroed
//   256:       bhist     1280 (int)    -- zeroed
//   1536:      ab         256 (float)
//   1792:      gbase_n    800 (int)    [783 used, sentinel at 782]
//   2592:      gbase_c    416 (int)    [392 used]
//   3008:      gcur_n     800 (int)
//   3808:      gcur_c     416 (int)
//   4224:      off_node 100004 (int)   [100001 used]
//   104228:    off_cstr  50004 (int)   [50001 used]
//   154232:    xcb     1600000 (bf16 normalized cstr feats, 50000x64)
//   1754232:   xnb     3200000 (bf16 normalized var  feats, 100000x64)
//   4954232:   ent_n   2000000 (int2; passA: {src17|dlow7<<17,w} -> sort: {src,w})
//   6954232:   ent_c   2000000 (int2; sorted in place)
// agg rows live in d_out; out_k rewrites d_out in place.
// ---------------------------------------------------------------------------
#define OFF_STATS  0
#define OFF_BHIST  256
#define OFF_AB     1536
#define OFF_GBN    1792
#define OFF_GBC    2592
#define OFF_GCN    3008
#define OFF_GCC    3808
#define OFF_OFF_N  4224
#define OFF_OFF_C  104228
#define OFF_XCB    154232
#define OFF_XNB    1754232
#define OFF_ENT_N  4954232
#define OFF_ENT_C  6954232
#define WS_ZERO_N  1536

// ---------------------------------------------------------------------------
// BN column stats.
// ---------------------------------------------------------------------------
__global__ __launch_bounds__(256) void bn_stats_k(const float* __restrict__ x, int n,
                                                  float* __restrict__ stats) {
  int c = threadIdx.x & 63;
  int rg = threadIdx.x >> 6;
  float s = 0.f, q = 0.f;
  for (int r = blockIdx.x * 4 + rg; r < n; r += gridDim.x * 4) {
    float v = x[r * DIM + c];
    s += v;
    q += v * v;
  }
  __shared__ float sb[256], qb[256];
  sb[threadIdx.x] = s;
  qb[threadIdx.x] = q;
  __syncthreads();
  if (rg == 0) {
    s = sb[c] + sb[c + 64] + sb[c + 128] + sb[c + 192];
    q = qb[c] + qb[c + 64] + qb[c + 128] + qb[c + 192];
    atomicAdd(&stats[c], s);
    atomicAdd(&stats[64 + c], q);
  }
}

__global__ void bn_finalize_k(const float* __restrict__ stats,
                              const float* __restrict__ gn, const float* __restrict__ bn,
                              const float* __restrict__ gc, const float* __restrict__ bc,
                              float* __restrict__ ab) {
  int t = threadIdx.x;  // 0..127
  int c = t & 63;
  bool isC = t >= 64;
  const float* st = stats + (isC ? 128 : 0);
  float n = isC ? (float)N_CSTR : (float)N_VAR;
  float mean = st[c] / n;
  float var = st[64 + c] / n - mean * mean;
  float g = isC ? gc[c] : gn[c];
  float be = isC ? bc[c] : bn[c];
  float a = g * rsqrtf(var + 1e-5f);
  float b = be - mean * a;
  float* o = ab + (isC ? 128 : 0);
  o[c] = a;
  o[64 + c] = b;
}

// ---------------------------------------------------------------------------
// bf16 round-to-nearest-even + normalized table build.
// ---------------------------------------------------------------------------
__device__ __forceinline__ unsigned short f2bf(float f) {
  unsigned u = __float_as_uint(f);
  return (unsigned short)((u + 0x7FFFu + ((u >> 16) & 1u)) >> 16);
}

__global__ __launch_bounds__(256) void cvt_k(const float4* __restrict__ src4,
                                             const float* __restrict__ ab,
                                             ushort4* __restrict__ dst, int n4) {
  int i4 = blockIdx.x * 256 + threadIdx.x;
  if (i4 >= n4) return;
  float4 v = src4[i4];
  int c0 = (i4 << 2) & 63;
  ushort4 o;
  o.x = f2bf(fmaf(v.x, ab[c0 + 0], ab[64 + c0 + 0]));
  o.y = f2bf(fmaf(v.y, ab[c0 + 1], ab[64 + c0 + 1]));
  o.z = f2bf(fmaf(v.z, ab[c0 + 2], ab[64 + c0 + 2]));
  o.w = f2bf(fmaf(v.w, ab[c0 + 3], ab[64 + c0 + 3]));
  dst[i4] = o;
}

// ---------------------------------------------------------------------------
// Coarse bucket histogram (both sides), LDS-aggregated.
// ---------------------------------------------------------------------------
__global__ __launch_bounds__(256) void bhist_k(const int4* __restrict__ es4,
                                               const int4* __restrict__ ed4,
                                               int* __restrict__ ws) {
  __shared__ int h[1280];
  for (int i = threadIdx.x; i < 1280; i += 256) h[i] = 0;
  __syncthreads();
  int stride = gridDim.x * 256;
  for (int i4 = blockIdx.x * 256 + threadIdx.x; i4 < NEDGE / 4; i4 += stride) {
    int4 d = ed4[i4];
    int4 s = es4[i4];
    atomicAdd(&h[d.x >> 7], 1);
    atomicAdd(&h[d.y >> 7], 1);
    atomicAdd(&h[d.z >> 7], 1);
    atomicAdd(&h[d.w >> 7], 1);
    atomicAdd(&h[NBK_N + (s.x >> 7)], 1);
    atomicAdd(&h[NBK_N + (s.y >> 7)], 1);
    atomicAdd(&h[NBK_N + (s.z >> 7)], 1);
    atomicAdd(&h[NBK_N + (s.w >> 7)], 1);
  }
  __syncthreads();
  int* gh = ws + OFF_BHIST;
  for (int i = threadIdx.x; i < NBK_T; i += 256)
    if (h[i]) atomicAdd(&gh[i], h[i]);
}

// ---------------------------------------------------------------------------
// Scan bucket counts -> gbase (+sentinel) and gcur; seed off sentinels. One WG.
// ---------------------------------------------------------------------------
__global__ __launch_bounds__(256) void bscan_k(int* __restrict__ ws) {
  __shared__ int sb[256];
  int t = threadIdx.x;
#pragma unroll
  for (int seg = 0; seg < 2; ++seg) {
    int nbk = seg ? NBK_C : NBK_N;
    const int* h = ws + OFF_BHIST + (seg ? NBK_N : 0);
    int* gb = ws + (seg ? OFF_GBC : OFF_GBN);
    int* gc = ws + (seg ? OFF_GCC : OFF_GCN);
    int base = t * 4;
    int c[4];
    int s0 = 0;
#pragma unroll
    for (int j = 0; j < 4; ++j) {
      c[j] = (base + j < nbk) ? h[base + j] : 0;
      s0 += c[j];
    }
    sb[t] = s0;
    __syncthreads();
    for (int d = 1; d < 256; d <<= 1) {
      int v = (t >= d) ? sb[t - d] : 0;
      __syncthreads();
      sb[t] += v;
      __syncthreads();
    }
    int ex = sb[t] - s0;
#pragma unroll
    for (int j = 0; j < 4; ++j) {
      if (base + j < nbk) {
        gb[base + j] = ex;
        gc[base + j] = ex;
      }
      ex += c[j];
    }
    if (t == 255) gb[nbk] = sb[255];  // sentinel = NEDGE
    __syncthreads();
  }
  if (t == 0) {
    ws[OFF_OFF_N + N_VAR] = NEDGE;
    ws[OFF_OFF_C + N_CSTR] = NEDGE;
  }
}

// ---------------------------------------------------------------------------
// Pass A: LDS multi-split of 4096-edge chunks into coarse buckets.
// Aggregated run allocation + run-contiguous flush. (Validated round 7.)
// ---------------------------------------------------------------------------
__global__ __launch_bounds__(256) void passA_k(const int4* __restrict__ es4,
                                               const int4* __restrict__ ed4,
                                               const float4* __restrict__ ea4,
                                               int* __restrict__ ws) {
  __shared__ int cntL[1024];
  __shared__ int runoffL[1024];
  __shared__ int gblL[1024];
  __shared__ int2 dataL[4096];
  __shared__ unsigned short bidL[4096];
  __shared__ int sbL[256];
  int side = (blockIdx.x >= NCHUNK);
  int chunk = side ? blockIdx.x - NCHUNK : blockIdx.x;
  int nbk = side ? NBK_C : NBK_N;
  int* gcur = ws + (side ? OFF_GCC : OFF_GCN);
  int2* ent = (int2*)(ws + (side ? OFF_ENT_C : OFF_ENT_N));
  int t = threadIdx.x;
  for (int i = t; i < 1024; i += 256) cntL[i] = 0;
  __syncthreads();
  int e0 = chunk * 4096;
  int base4 = chunk * 1024 + t * 4;
  int pk[16];
  int2 pay[16];
#pragma unroll
  for (int j = 0; j < 4; ++j) {
    int i4 = base4 + j;
    if (i4 < NEDGE / 4) {
      int4 sv = es4[i4];
      int4 dv = ed4[i4];
      float4 wv = ea4[i4];
      int ss[4] = {sv.x, sv.y, sv.z, sv.w};
      int dd[4] = {dv.x, dv.y, dv.z, dv.w};
      float ww[4] = {wv.x, wv.y, wv.z, wv.w};
#pragma unroll
      for (int k = 0; k < 4; ++k) {
        int s = ss[k], d = dd[k];
        int b = side ? (s >> 7) : (d >> 7);
        int pl = side ? (d | ((s & 127) << 17)) : (s | ((d & 127) << 17));
        int rank = atomicAdd(&cntL[b], 1);
        pk[j * 4 + k] = b * 4096 + rank;
        pay[j * 4 + k] = make_int2(pl, __float_as_int(ww[k]));
      }
    } else {
#pragma unroll
      for (int k = 0; k < 4; ++k) pk[j * 4 + k] = -1;
    }
  }
  __syncthreads();
  int base = t * 4;
  int c[4];
  int s0 = 0;
#pragma unroll
  for (int j = 0; j < 4; ++j) {
    c[j] = cntL[base + j];
    s0 += c[j];
  }
  sbL[t] = s0;
  __syncthreads();
  for (int d = 1; d < 256; d <<= 1) {
    int v = (t >= d) ? sbL[t - d] : 0;
    __syncthreads();
    sbL[t] += v;
    __syncthreads();
  }
  int ex = sbL[t] - s0;
#pragma unroll
  for (int j = 0; j < 4; ++j) {
    runoffL[base + j] = ex;
    ex += c[j];
  }
  __syncthreads();
  for (int b = t; b < nbk; b += 256) {
    int cc = cntL[b];
    gblL[b] = cc ? atomicAdd(&gcur[b], cc) : 0;
  }
  __syncthreads();
#pragma unroll
  for (int j = 0; j < 16; ++j) {
    if (pk[j] >= 0) {
      int b = pk[j] >> 12;
      int slot = runoffL[b] + (pk[j] & 4095);
      dataL[slot] = pay[j];
      bidL[slot] = (unsigned short)b;
    }
  }
  __syncthreads();
  int chunkN = min(4096, NEDGE - e0);
  for (int i = t; i < chunkN; i += 256) {
    int b = bidL[i];
    ent[gblL[b] + (i - runoffL[b])] = dataL[i];
  }
}

// ---------------------------------------------------------------------------
// Per-bucket in-LDS counting sort -> fully sorted CSR, in place.
// One WG per bucket: stage entries (<=4096; measured max ~2800 at 30 sigma),
// 128-bin count + scan + rank, write back {src,w} contiguous per dst node,
// emit off[] for this bucket's 128 rows.
// ---------------------------------------------------------------------------
__global__ __launch_bounds__(256) void sort_k(int* __restrict__ ws) {
  __shared__ int2 data[4096];
  __shared__ int hcnt[128], hrank[128];
  __shared__ int sb[128];
  int x = blockIdx.x;
  int side = (x >= NBK_N);
  int bk = side ? x - NBK_N : x;
  const int* gbase = ws + (side ? OFF_GBC : OFF_GBN);
  int2* ent = (int2*)(ws + (side ? OFF_ENT_C : OFF_ENT_N));
  int* off = ws + (side ? OFF_OFF_C : OFF_OFF_N);
  int n = side ? N_CSTR : N_VAR;
  int t = threadIdx.x;
  int beg = gbase[bk], end = gbase[bk + 1];
  int cnt = end - beg;
  if (t < 128) hcnt[t] = 0;
  __syncthreads();
  for (int i = t; i < cnt; i += 256) {
    int2 e = ent[beg + i];
    data[i] = e;
    atomicAdd(&hcnt[(e.x >> 17) & 127], 1);
  }
  __syncthreads();
  if (t < 128) sb[t] = hcnt[t];
  __syncthreads();
  for (int d = 1; d < 128; d <<= 1) {
    int v = 0;
    if (t < 128 && t >= d) v = sb[t - d];
    __syncthreads();
    if (t < 128) sb[t] += v;
    __syncthreads();
  }
  if (t < 128) {
    int ex = sb[t] - hcnt[t];
    hrank[t] = ex;
    int r = bk * 128 + t;
    if (r < n) off[r] = beg + ex;
  }
  __syncthreads();
  for (int i = t; i < cnt; i += 256) {
    int2 e = data[i];
    int dl = (e.x >> 17) & 127;
    int pos = atomicAdd(&hrank[dl], 1);
    ent[beg + pos] = make_int2(e.x & 0x1FFFF, e.y);
  }
}

// ---------------------------------------------------------------------------
// Gather from sorted CSR: one wave per row, lane = column, unroll-8.
// Source rows come from the bf16 normalized table (128 B/row gathers).
// ---------------------------------------------------------------------------
__global__ __launch_bounds__(256) void gather_k(
    const unsigned short* __restrict__ tab, const int2* __restrict__ ent,
    const int* __restrict__ off, float* __restrict__ agg, int n) {
  int lane = threadIdx.x & 63;
  int r = __builtin_amdgcn_readfirstlane((blockIdx.x * blockDim.x + threadIdx.x) >> 6);
  if (r >= n) return;
  int beg = off[r], end = off[r + 1];
  float acc0 = 0.f, acc1 = 0.f;
  int e = beg;
#define BF(hv) __uint_as_float(((unsigned)(hv)) << 16)
  if (e < end && (e & 1)) {
    int2 p = ent[e];
    acc0 = fmaf(BF(tab[p.x * DIM + lane]), __int_as_float(p.y), acc0);
    ++e;
  }
  for (; e + 8 <= end; e += 8) {
    int4 p0 = *reinterpret_cast<const int4*>(&ent[e]);
    int4 p1 = *reinterpret_cast<const int4*>(&ent[e + 2]);
    int4 p2 = *reinterpret_cast<const int4*>(&ent[e + 4]);
    int4 p3 = *reinterpret_cast<const int4*>(&ent[e + 6]);
    float v0 = BF(tab[p0.x * DIM + lane]);
    float v1 = BF(tab[p0.z * DIM + lane]);
    float v2 = BF(tab[p1.x * DIM + lane]);
    float v3 = BF(tab[p1.z * DIM + lane]);
    float v4 = BF(tab[p2.x * DIM + lane]);
    float v5 = BF(tab[p2.z * DIM + lane]);
    float v6 = BF(tab[p3.x * DIM + lane]);
    float v7 = BF(tab[p3.z * DIM + lane]);
    acc0 = fmaf(v0, __int_as_float(p0.y), acc0);
    acc1 = fmaf(v1, __int_as_float(p0.w), acc1);
    acc0 = fmaf(v2, __int_as_float(p1.y), acc0);
    acc1 = fmaf(v3, __int_as_float(p1.w), acc1);
    acc0 = fmaf(v4, __int_as_float(p2.y), acc0);
    acc1 = fmaf(v5, __int_as_float(p2.w), acc1);
    acc0 = fmaf(v6, __int_as_float(p3.y), acc0);
    acc1 = fmaf(v7, __int_as_float(p3.w), acc1);
  }
  for (; e + 2 <= end; e += 2) {
    int4 p = *reinterpret_cast<const int4*>(&ent[e]);
    acc0 = fmaf(BF(tab[p.x * DIM + lane]), __int_as_float(p.y), acc0);
    acc1 = fmaf(BF(tab[p.z * DIM + lane]), __int_as_float(p.w), acc1);
  }
  if (e < end) {
    int2 p = ent[e];
    acc0 = fmaf(BF(tab[p.x * DIM + lane]), __int_as_float(p.y), acc0);
  }
#undef BF
  agg[(long)r * DIM + lane] = (acc0 + acc1) / fmaxf((float)(end - beg), 1.f);
}

// ---------------------------------------------------------------------------
// Output GEMM + epilogue in place; weights in registers, readlane broadcast.
// ---------------------------------------------------------------------------
__global__ __launch_bounds__(256) void out_k(
    const float* __restrict__ raw, const float* __restrict__ ab,
    const float* __restrict__ w_rel, const float* __restrict__ b_rel,
    const float* __restrict__ w_root, float* __restrict__ io, int n) {
  int lane = threadIdx.x & 63;
  float a = ab[lane], b = ab[64 + lane];
  float brel = b_rel[lane];
  float4 wr[16], wo[16];
#pragma unroll
  for (int i = 0; i < 16; ++i) {
    wr[i] = reinterpret_cast<const float4*>(w_rel + lane * DIM)[i];
    wo[i] = reinterpret_cast<const float4*>(w_root + lane * DIM)[i];
  }
  int wave = (blockIdx.x * blockDim.x + threadIdx.x) >> 6;
  int nw = (gridDim.x * blockDim.x) >> 6;
  for (int r = wave; r < n; r += nw) {
    float av = io[r * DIM + lane];
    float xv = fmaf(raw[r * DIM + lane], a, b);
    int avi = __float_as_int(av);
    int xvi = __float_as_int(xv);
    float acc0 = 0.f, acc1 = 0.f, acc2 = 0.f, acc3 = 0.f;
#pragma unroll
    for (int i = 0; i < 16; ++i) {
      acc0 = fmaf(__int_as_float(__builtin_amdgcn_readlane(avi, 4 * i + 0)), wr[i].x, acc0);
      acc1 = fmaf(__int_as_float(__builtin_amdgcn_readlane(avi, 4 * i + 1)), wr[i].y, acc1);
      acc2 = fmaf(__int_as_float(__builtin_amdgcn_readlane(avi, 4 * i + 2)), wr[i].z, acc2);
      acc3 = fmaf(__int_as_float(__builtin_amdgcn_readlane(avi, 4 * i + 3)), wr[i].w, acc3);
      acc0 = fmaf(__int_as_float(__builtin_amdgcn_readlane(xvi, 4 * i + 0)), wo[i].x, acc0);
      acc1 = fmaf(__int_as_float(__builtin_amdgcn_readlane(xvi, 4 * i + 1)), wo[i].y, acc1);
      acc2 = fmaf(__int_as_float(__builtin_amdgcn_readlane(xvi, 4 * i + 2)), wo[i].z, acc2);
      acc3 = fmaf(__int_as_float(__builtin_amdgcn_readlane(xvi, 4 * i + 3)), wo[i].w, acc3);
    }
    io[r * DIM + lane] = fmaxf((acc0 + acc1) + (acc2 + acc3) + brel + xv, 0.f);
  }
}

extern "C" void kernel_launch(void* const* d_in, const int* in_sizes, int n_in,
                              void* d_out, int out_size, void* d_ws, size_t ws_size,
                              hipStream_t stream) {
  const float* vf = (const float*)d_in[0];
  const float* cf = (const float*)d_in[1];
  const int* es = (const int*)d_in[2];
  const int* ed = (const int*)d_in[3];
  const float* ea = (const float*)d_in[4];
  const float* gn = (const float*)d_in[5];
  const float* bn = (const float*)d_in[6];
  const float* gc = (const float*)d_in[7];
  const float* bc = (const float*)d_in[8];
  const float* n_rel_w = (const float*)d_in[9];
  const float* n_rel_b = (const float*)d_in[10];
  const float* n_root_w = (const float*)d_in[11];
  const float* c_rel_w = (const float*)d_in[12];
  const float* c_rel_b = (const float*)d_in[13];
  const float* c_root_w = (const float*)d_in[14];
  float* out = (float*)d_out;
  int* wsi = (int*)d_ws;
  float* wsf = (float*)d_ws;

  float* stats = wsf + OFF_STATS;
  float* ab = wsf + OFF_AB;
  ushort4* xcb = (ushort4*)(wsi + OFF_XCB);
  ushort4* xnb = (ushort4*)(wsi + OFF_XNB);
  const unsigned short* xcb_s = (const unsigned short*)(wsi + OFF_XCB);
  const unsigned short* xnb_s = (const unsigned short*)(wsi + OFF_XNB);
  const int2* ent_n = (const int2*)(wsi + OFF_ENT_N);
  const int2* ent_c = (const int2*)(wsi + OFF_ENT_C);

  float* agg_node = out;
  float* agg_cstr = out + (long)N_VAR * DIM;

  hipMemsetAsync(d_ws, 0, (size_t)WS_ZERO_N * sizeof(int), stream);

  bn_stats_k<<<512, 256, 0, stream>>>(vf, N_VAR, stats);
  bn_stats_k<<<512, 256, 0, stream>>>(cf, N_CSTR, stats + 128);
  bn_finalize_k<<<1, 128, 0, stream>>>(stats, gn, bn, gc, bc, ab);

  cvt_k<<<(N_CSTR * DIM / 4 + 255) / 256, 256, 0, stream>>>((const float4*)cf, ab + 128,
                                                            xcb, N_CSTR * DIM / 4);
  cvt_k<<<(N_VAR * DIM / 4 + 255) / 256, 256, 0, stream>>>((const float4*)vf, ab,
                                                           xnb, N_VAR * DIM / 4);

  bhist_k<<<128, 256, 0, stream>>>((const int4*)es, (const int4*)ed, wsi);
  bscan_k<<<1, 256, 0, stream>>>(wsi);
  passA_k<<<2 * NCHUNK, 256, 0, stream>>>((const int4*)es, (const int4*)ed,
                                          (const float4*)ea, wsi);
  sort_k<<<NBK_T, 256, 0, stream>>>(wsi);

  gather_k<<<(N_VAR + 3) / 4, 256, 0, stream>>>(xcb_s, ent_n, wsi + OFF_OFF_N,
                                                agg_node, N_VAR);
  gather_k<<<(N_CSTR + 3) / 4, 256, 0, stream>>>(xnb_s, ent_c, wsi + OFF_OFF_C,
                                                 agg_cstr, N_CSTR);

  out_k<<<1024, 256, 0, stream>>>(vf, ab, n_rel_w, n_rel_b, n_root_w, agg_node, N_VAR);
  out_k<<<512, 256, 0, stream>>>(cf, ab + 128, c_rel_w, c_rel_b, c_root_w, agg_cstr,
                                 N_CSTR);
}

// Round 9
// 333.828 us; speedup vs baseline: 3.1548x; 1.1250x over previous
//
#include <hip/hip_runtime.h>

#define N_VAR   100000
#define N_CSTR  50000
#define NEDGE   1000000
#define DIM     64

// Coarse buckets: 128 destination nodes each.
#define NBK_N 782           // ceil(100000/128)
#define NBK_C 391           // ceil(50000/128)
#define NBK_T 1173
#define NCHUNK 245          // ceil(1e6/4096) pass-A chunks per side

// ---------------------------------------------------------------------------
// Workspace layout (4-byte units), ~35.8 MB total:
//   0:         stats      256 (float)  -- zeroed
//   256:       bhist     1280 (int)    -- zeroed
//   1536:      ab         256 (float)
//   1792:      gbase_n    800 (int)
//   2592:      gbase_c    416 (int)
//   3008:      gcur_n     800 (int)
//   3808:      gcur_c     416 (int)
//   4224:      off_node 100004 (int)
//   104228:    off_cstr  50004 (int)
//   154232:    xcb     1600000 (bf16 normalized cstr feats, 50000x64)
//   1754232:   xnb     3200000 (bf16 normalized var  feats, 100000x64)
//   4954232:   ent_n   2000000 (int2)
//   6954232:   ent_c   2000000 (int2)
// agg rows live in d_out; out_mfma_k rewrites d_out in place.
// ---------------------------------------------------------------------------
#define OFF_STATS  0
#define OFF_BHIST  256
#define OFF_AB     1536
#define OFF_GBN    1792
#define OFF_GBC    2592
#define OFF_GCN    3008
#define OFF_GCC    3808
#define OFF_OFF_N  4224
#define OFF_OFF_C  104228
#define OFF_XCB    154232
#define OFF_XNB    1754232
#define OFF_ENT_N  4954232
#define OFF_ENT_C  6954232
#define WS_ZERO_N  1536

typedef __attribute__((ext_vector_type(8))) short bf16x8;
typedef __attribute__((ext_vector_type(4))) float f32x4;

// ---------------------------------------------------------------------------
// BN column stats.
// ---------------------------------------------------------------------------
__global__ __launch_bounds__(256) void bn_stats_k(const float* __restrict__ x, int n,
                                                  float* __restrict__ stats) {
  int c = threadIdx.x & 63;
  int rg = threadIdx.x >> 6;
  float s = 0.f, q = 0.f;
  for (int r = blockIdx.x * 4 + rg; r < n; r += gridDim.x * 4) {
    float v = x[r * DIM + c];
    s += v;
    q += v * v;
  }
  __shared__ float sb[256], qb[256];
  sb[threadIdx.x] = s;
  qb[threadIdx.x] = q;
  __syncthreads();
  if (rg == 0) {
    s = sb[c] + sb[c + 64] + sb[c + 128] + sb[c + 192];
    q = qb[c] + qb[c + 64] + qb[c + 128] + qb[c + 192];
    atomicAdd(&stats[c], s);
    atomicAdd(&stats[64 + c], q);
  }
}

__global__ void bn_finalize_k(const float* __restrict__ stats,
                              const float* __restrict__ gn, const float* __restrict__ bn,
                              const float* __restrict__ gc, const float* __restrict__ bc,
                              float* __restrict__ ab) {
  int t = threadIdx.x;  // 0..127
  int c = t & 63;
  bool isC = t >= 64;
  const float* st = stats + (isC ? 128 : 0);
  float n = isC ? (float)N_CSTR : (float)N_VAR;
  float mean = st[c] / n;
  float var = st[64 + c] / n - mean * mean;
  float g = isC ? gc[c] : gn[c];
  float be = isC ? bc[c] : bn[c];
  float a = g * rsqrtf(var + 1e-5f);
  float b = be - mean * a;
  float* o = ab + (isC ? 128 : 0);
  o[c] = a;
  o[64 + c] = b;
}

// ---------------------------------------------------------------------------
// bf16 round-to-nearest-even + normalized table build.
// ---------------------------------------------------------------------------
__device__ __forceinline__ unsigned short f2bf(float f) {
  unsigned u = __float_as_uint(f);
  return (unsigned short)((u + 0x7FFFu + ((u >> 16) & 1u)) >> 16);
}

__global__ __launch_bounds__(256) void cvt_k(const float4* __restrict__ src4,
                                             const float* __restrict__ ab,
                                             ushort4* __restrict__ dst, int n4) {
  int i4 = blockIdx.x * 256 + threadIdx.x;
  if (i4 >= n4) return;
  float4 v = src4[i4];
  int c0 = (i4 << 2) & 63;
  ushort4 o;
  o.x = f2bf(fmaf(v.x, ab[c0 + 0], ab[64 + c0 + 0]));
  o.y = f2bf(fmaf(v.y, ab[c0 + 1], ab[64 + c0 + 1]));
  o.z = f2bf(fmaf(v.z, ab[c0 + 2], ab[64 + c0 + 2]));
  o.w = f2bf(fmaf(v.w, ab[c0 + 3], ab[64 + c0 + 3]));
  dst[i4] = o;
}

// ---------------------------------------------------------------------------
// Coarse bucket histogram (both sides), LDS-aggregated.
// ---------------------------------------------------------------------------
__global__ __launch_bounds__(256) void bhist_k(const int4* __restrict__ es4,
                                               const int4* __restrict__ ed4,
                                               int* __restrict__ ws) {
  __shared__ int h[1280];
  for (int i = threadIdx.x; i < 1280; i += 256) h[i] = 0;
  __syncthreads();
  int stride = gridDim.x * 256;
  for (int i4 = blockIdx.x * 256 + threadIdx.x; i4 < NEDGE / 4; i4 += stride) {
    int4 d = ed4[i4];
    int4 s = es4[i4];
    atomicAdd(&h[d.x >> 7], 1);
    atomicAdd(&h[d.y >> 7], 1);
    atomicAdd(&h[d.z >> 7], 1);
    atomicAdd(&h[d.w >> 7], 1);
    atomicAdd(&h[NBK_N + (s.x >> 7)], 1);
    atomicAdd(&h[NBK_N + (s.y >> 7)], 1);
    atomicAdd(&h[NBK_N + (s.z >> 7)], 1);
    atomicAdd(&h[NBK_N + (s.w >> 7)], 1);
  }
  __syncthreads();
  int* gh = ws + OFF_BHIST;
  for (int i = threadIdx.x; i < NBK_T; i += 256)
    if (h[i]) atomicAdd(&gh[i], h[i]);
}

// ---------------------------------------------------------------------------
// Scan bucket counts -> gbase (+sentinel) and gcur; seed off sentinels. One WG.
// ---------------------------------------------------------------------------
__global__ __launch_bounds__(256) void bscan_k(int* __restrict__ ws) {
  __shared__ int sb[256];
  int t = threadIdx.x;
#pragma unroll
  for (int seg = 0; seg < 2; ++seg) {
    int nbk = seg ? NBK_C : NBK_N;
    const int* h = ws + OFF_BHIST + (seg ? NBK_N : 0);
    int* gb = ws + (seg ? OFF_GBC : OFF_GBN);
    int* gc = ws + (seg ? OFF_GCC : OFF_GCN);
    int base = t * 4;
    int c[4];
    int s0 = 0;
#pragma unroll
    for (int j = 0; j < 4; ++j) {
      c[j] = (base + j < nbk) ? h[base + j] : 0;
      s0 += c[j];
    }
    sb[t] = s0;
    __syncthreads();
    for (int d = 1; d < 256; d <<= 1) {
      int v = (t >= d) ? sb[t - d] : 0;
      __syncthreads();
      sb[t] += v;
      __syncthreads();
    }
    int ex = sb[t] - s0;
#pragma unroll
    for (int j = 0; j < 4; ++j) {
      if (base + j < nbk) {
        gb[base + j] = ex;
        gc[base + j] = ex;
      }
      ex += c[j];
    }
    if (t == 255) gb[nbk] = sb[255];  // sentinel = NEDGE
    __syncthreads();
  }
  if (t == 0) {
    ws[OFF_OFF_N + N_VAR] = NEDGE;
    ws[OFF_OFF_C + N_CSTR] = NEDGE;
  }
}

// ---------------------------------------------------------------------------
// Pass A: LDS multi-split of 4096-edge chunks into coarse buckets.
// ---------------------------------------------------------------------------
__global__ __launch_bounds__(256) void passA_k(const int4* __restrict__ es4,
                                               const int4* __restrict__ ed4,
                                               const float4* __restrict__ ea4,
                                               int* __restrict__ ws) {
  __shared__ int cntL[1024];
  __shared__ int runoffL[1024];
  __shared__ int gblL[1024];
  __shared__ int2 dataL[4096];
  __shared__ unsigned short bidL[4096];
  __shared__ int sbL[256];
  int side = (blockIdx.x >= NCHUNK);
  int chunk = side ? blockIdx.x - NCHUNK : blockIdx.x;
  int nbk = side ? NBK_C : NBK_N;
  int* gcur = ws + (side ? OFF_GCC : OFF_GCN);
  int2* ent = (int2*)(ws + (side ? OFF_ENT_C : OFF_ENT_N));
  int t = threadIdx.x;
  for (int i = t; i < 1024; i += 256) cntL[i] = 0;
  __syncthreads();
  int e0 = chunk * 4096;
  int base4 = chunk * 1024 + t * 4;
  int pk[16];
  int2 pay[16];
#pragma unroll
  for (int j = 0; j < 4; ++j) {
    int i4 = base4 + j;
    if (i4 < NEDGE / 4) {
      int4 sv = es4[i4];
      int4 dv = ed4[i4];
      float4 wv = ea4[i4];
      int ss[4] = {sv.x, sv.y, sv.z, sv.w};
      int dd[4] = {dv.x, dv.y, dv.z, dv.w};
      float ww[4] = {wv.x, wv.y, wv.z, wv.w};
#pragma unroll
      for (int k = 0; k < 4; ++k) {
        int s = ss[k], d = dd[k];
        int b = side ? (s >> 7) : (d >> 7);
        int pl = side ? (d | ((s & 127) << 17)) : (s | ((d & 127) << 17));
        int rank = atomicAdd(&cntL[b], 1);
        pk[j * 4 + k] = b * 4096 + rank;
        pay[j * 4 + k] = make_int2(pl, __float_as_int(ww[k]));
      }
    } else {
#pragma unroll
      for (int k = 0; k < 4; ++k) pk[j * 4 + k] = -1;
    }
  }
  __syncthreads();
  int base = t * 4;
  int c[4];
  int s0 = 0;
#pragma unroll
  for (int j = 0; j < 4; ++j) {
    c[j] = cntL[base + j];
    s0 += c[j];
  }
  sbL[t] = s0;
  __syncthreads();
  for (int d = 1; d < 256; d <<= 1) {
    int v = (t >= d) ? sbL[t - d] : 0;
    __syncthreads();
    sbL[t] += v;
    __syncthreads();
  }
  int ex = sbL[t] - s0;
#pragma unroll
  for (int j = 0; j < 4; ++j) {
    runoffL[base + j] = ex;
    ex += c[j];
  }
  __syncthreads();
  for (int b = t; b < nbk; b += 256) {
    int cc = cntL[b];
    gblL[b] = cc ? atomicAdd(&gcur[b], cc) : 0;
  }
  __syncthreads();
#pragma unroll
  for (int j = 0; j < 16; ++j) {
    if (pk[j] >= 0) {
      int b = pk[j] >> 12;
      int slot = runoffL[b] + (pk[j] & 4095);
      dataL[slot] = pay[j];
      bidL[slot] = (unsigned short)b;
    }
  }
  __syncthreads();
  int chunkN = min(4096, NEDGE - e0);
  for (int i = t; i < chunkN; i += 256) {
    int b = bidL[i];
    ent[gblL[b] + (i - runoffL[b])] = dataL[i];
  }
}

// ---------------------------------------------------------------------------
// Per-bucket in-LDS counting sort -> fully sorted CSR, in place.
// ---------------------------------------------------------------------------
__global__ __launch_bounds__(256) void sort_k(int* __restrict__ ws) {
  __shared__ int2 data[4096];
  __shared__ int hcnt[128], hrank[128];
  __shared__ int sb[128];
  int x = blockIdx.x;
  int side = (x >= NBK_N);
  int bk = side ? x - NBK_N : x;
  const int* gbase = ws + (side ? OFF_GBC : OFF_GBN);
  int2* ent = (int2*)(ws + (side ? OFF_ENT_C : OFF_ENT_N));
  int* off = ws + (side ? OFF_OFF_C : OFF_OFF_N);
  int n = side ? N_CSTR : N_VAR;
  int t = threadIdx.x;
  int beg = gbase[bk], end = gbase[bk + 1];
  int cnt = end - beg;
  if (t < 128) hcnt[t] = 0;
  __syncthreads();
  for (int i = t; i < cnt; i += 256) {
    int2 e = ent[beg + i];
    data[i] = e;
    atomicAdd(&hcnt[(e.x >> 17) & 127], 1);
  }
  __syncthreads();
  if (t < 128) sb[t] = hcnt[t];
  __syncthreads();
  for (int d = 1; d < 128; d <<= 1) {
    int v = 0;
    if (t < 128 && t >= d) v = sb[t - d];
    __syncthreads();
    if (t < 128) sb[t] += v;
    __syncthreads();
  }
  if (t < 128) {
    int ex = sb[t] - hcnt[t];
    hrank[t] = ex;
    int r = bk * 128 + t;
    if (r < n) off[r] = beg + ex;
  }
  __syncthreads();
  for (int i = t; i < cnt; i += 256) {
    int2 e = data[i];
    int dl = (e.x >> 17) & 127;
    int pos = atomicAdd(&hrank[dl], 1);
    ent[beg + pos] = make_int2(e.x & 0x1FFFF, e.y);
  }
}

// ---------------------------------------------------------------------------
// Gather from sorted CSR: one wave per row, lane = column, unroll-8.
// ---------------------------------------------------------------------------
__global__ __launch_bounds__(256) void gather_k(
    const unsigned short* __restrict__ tab, const int2* __restrict__ ent,
    const int* __restrict__ off, float* __restrict__ agg, int n) {
  int lane = threadIdx.x & 63;
  int r = __builtin_amdgcn_readfirstlane((blockIdx.x * blockDim.x + threadIdx.x) >> 6);
  if (r >= n) return;
  int beg = off[r], end = off[r + 1];
  float acc0 = 0.f, acc1 = 0.f;
  int e = beg;
#define BF(hv) __uint_as_float(((unsigned)(hv)) << 16)
  if (e < end && (e & 1)) {
    int2 p = ent[e];
    acc0 = fmaf(BF(tab[p.x * DIM + lane]), __int_as_float(p.y), acc0);
    ++e;
  }
  for (; e + 8 <= end; e += 8) {
    int4 p0 = *reinterpret_cast<const int4*>(&ent[e]);
    int4 p1 = *reinterpret_cast<const int4*>(&ent[e + 2]);
    int4 p2 = *reinterpret_cast<const int4*>(&ent[e + 4]);
    int4 p3 = *reinterpret_cast<const int4*>(&ent[e + 6]);
    float v0 = BF(tab[p0.x * DIM + lane]);
    float v1 = BF(tab[p0.z * DIM + lane]);
    float v2 = BF(tab[p1.x * DIM + lane]);
    float v3 = BF(tab[p1.z * DIM + lane]);
    float v4 = BF(tab[p2.x * DIM + lane]);
    float v5 = BF(tab[p2.z * DIM + lane]);
    float v6 = BF(tab[p3.x * DIM + lane]);
    float v7 = BF(tab[p3.z * DIM + lane]);
    acc0 = fmaf(v0, __int_as_float(p0.y), acc0);
    acc1 = fmaf(v1, __int_as_float(p0.w), acc1);
    acc0 = fmaf(v2, __int_as_float(p1.y), acc0);
    acc1 = fmaf(v3, __int_as_float(p1.w), acc1);
    acc0 = fmaf(v4, __int_as_float(p2.y), acc0);
    acc1 = fmaf(v5, __int_as_float(p2.w), acc1);
    acc0 = fmaf(v6, __int_as_float(p3.y), acc0);
    acc1 = fmaf(v7, __int_as_float(p3.w), acc1);
  }
  for (; e + 2 <= end; e += 2) {
    int4 p = *reinterpret_cast<const int4*>(&ent[e]);
    acc0 = fmaf(BF(tab[p.x * DIM + lane]), __int_as_float(p.y), acc0);
    acc1 = fmaf(BF(tab[p.z * DIM + lane]), __int_as_float(p.w), acc1);
  }
  if (e < end) {
    int2 p = ent[e];
    acc0 = fmaf(BF(tab[p.x * DIM + lane]), __int_as_float(p.y), acc0);
  }
#undef BF
  agg[(long)r * DIM + lane] = (acc0 + acc1) / fmaxf((float)(end - beg), 1.f);
}

// ---------------------------------------------------------------------------
// MFMA output epilogue, in place on io (= agg rows):
//   out[r][c] = relu( [agg[r] | xv[r]] (K=128) . [w_rel[c] ; w_root[c]]
//               + b_rel[c] + xv[r][c] )
// One 16-row tile per wave per iteration; mfma_f32_16x16x32_bf16, K=128 in
// 4 chunks x 4 col-tiles = 16 MFMAs/tile. B (weights, bf16) built once in
// registers. A-frag layout: A[m=lane&15][k=quad*8+j]; B[k=quad*8+j][n=lane&15];
// D: col=lane&15, row=quad*4+reg (HW-verified mappings). Residual xv is
// recomputed in f32 at the D layout for exactness.
// ---------------------------------------------------------------------------
__global__ __launch_bounds__(256) void out_mfma_k(
    const float* __restrict__ raw, const float* __restrict__ ab,
    const float* __restrict__ w_rel, const float* __restrict__ b_rel,
    const float* __restrict__ w_root, float* __restrict__ io, int n) {
  int t = threadIdx.x;
  int lane = t & 63, wv = t >> 6;
  int quad = lane >> 4, l16 = lane & 15;

  // B fragments: bfrag[nt][kc] holds B[k=kc*32+quad*8+j][n=nt*16+l16]
  //            = W128[n][k], W128[c] = concat(w_rel[c][:], w_root[c][:]).
  bf16x8 bfrag[4][4];
#pragma unroll
  for (int nt = 0; nt < 4; ++nt) {
    int c = nt * 16 + l16;
#pragma unroll
    for (int kc = 0; kc < 4; ++kc) {
      int bk = kc * 32 + quad * 8;
      const float* wsrc = (bk < 64) ? (w_rel + c * 64 + bk) : (w_root + c * 64 + bk - 64);
      bf16x8 f;
#pragma unroll
      for (int j = 0; j < 8; ++j) f[j] = (short)f2bf(wsrc[j]);
      bfrag[nt][kc] = f;
    }
  }
  // BN coefficients for the xv A-chunks (cols quad*8+j and 32+quad*8+j).
  float av0[8], bv0[8], av1[8], bv1[8];
#pragma unroll
  for (int j = 0; j < 8; ++j) {
    av0[j] = ab[quad * 8 + j];
    bv0[j] = ab[64 + quad * 8 + j];
    av1[j] = ab[32 + quad * 8 + j];
    bv1[j] = ab[96 + quad * 8 + j];
  }

  int tiles = n >> 4;  // n is a multiple of 16 (100000, 50000)
  for (int tile = blockIdx.x * 4 + wv; tile < tiles; tile += gridDim.x * 4) {
    int r0 = tile << 4;
    const float* aggr = io + (long)(r0 + l16) * DIM;
    const float* rawr = raw + (long)(r0 + l16) * DIM;
    bf16x8 a0, a1, a2, a3;
#pragma unroll
    for (int j = 0; j < 8; ++j) {
      a0[j] = (short)f2bf(aggr[quad * 8 + j]);
      a1[j] = (short)f2bf(aggr[32 + quad * 8 + j]);
      a2[j] = (short)f2bf(fmaf(rawr[quad * 8 + j], av0[j], bv0[j]));
      a3[j] = (short)f2bf(fmaf(rawr[32 + quad * 8 + j], av1[j], bv1[j]));
    }
    f32x4 acc[4];
#pragma unroll
    for (int nt = 0; nt < 4; ++nt) {
      acc[nt] = (f32x4){0.f, 0.f, 0.f, 0.f};
      acc[nt] = __builtin_amdgcn_mfma_f32_16x16x32_bf16(a0, bfrag[nt][0], acc[nt], 0, 0, 0);
      acc[nt] = __builtin_amdgcn_mfma_f32_16x16x32_bf16(a1, bfrag[nt][1], acc[nt], 0, 0, 0);
      acc[nt] = __builtin_amdgcn_mfma_f32_16x16x32_bf16(a2, bfrag[nt][2], acc[nt], 0, 0, 0);
      acc[nt] = __builtin_amdgcn_mfma_f32_16x16x32_bf16(a3, bfrag[nt][3], acc[nt], 0, 0, 0);
    }
#pragma unroll
    for (int nt = 0; nt < 4; ++nt) {
      int c = nt * 16 + l16;
      float aC = ab[c], bC = ab[64 + c], brC = b_rel[c];
#pragma unroll
      for (int reg = 0; reg < 4; ++reg) {
        int r = r0 + quad * 4 + reg;
        float xv = fmaf(raw[(long)r * DIM + c], aC, bC);
        io[(long)r * DIM + c] = fmaxf(acc[nt][reg] + brC + xv, 0.f);
      }
    }
  }
}

extern "C" void kernel_launch(void* const* d_in, const int* in_sizes, int n_in,
                              void* d_out, int out_size, void* d_ws, size_t ws_size,
                              hipStream_t stream) {
  const float* vf = (const float*)d_in[0];
  const float* cf = (const float*)d_in[1];
  const int* es = (const int*)d_in[2];
  const int* ed = (const int*)d_in[3];
  const float* ea = (const float*)d_in[4];
  const float* gn = (const float*)d_in[5];
  const float* bn = (const float*)d_in[6];
  const float* gc = (const float*)d_in[7];
  const float* bc = (const float*)d_in[8];
  const float* n_rel_w = (const float*)d_in[9];
  const float* n_rel_b = (const float*)d_in[10];
  const float* n_root_w = (const float*)d_in[11];
  const float* c_rel_w = (const float*)d_in[12];
  const float* c_rel_b = (const float*)d_in[13];
  const float* c_root_w = (const float*)d_in[14];
  float* out = (float*)d_out;
  int* wsi = (int*)d_ws;
  float* wsf = (float*)d_ws;

  float* stats = wsf + OFF_STATS;
  float* ab = wsf + OFF_AB;
  ushort4* xcb = (ushort4*)(wsi + OFF_XCB);
  ushort4* xnb = (ushort4*)(wsi + OFF_XNB);
  const unsigned short* xcb_s = (const unsigned short*)(wsi + OFF_XCB);
  const unsigned short* xnb_s = (const unsigned short*)(wsi + OFF_XNB);
  const int2* ent_n = (const int2*)(wsi + OFF_ENT_N);
  const int2* ent_c = (const int2*)(wsi + OFF_ENT_C);

  float* agg_node = out;
  float* agg_cstr = out + (long)N_VAR * DIM;

  hipMemsetAsync(d_ws, 0, (size_t)WS_ZERO_N * sizeof(int), stream);

  bn_stats_k<<<512, 256, 0, stream>>>(vf, N_VAR, stats);
  bn_stats_k<<<512, 256, 0, stream>>>(cf, N_CSTR, stats + 128);
  bn_finalize_k<<<1, 128, 0, stream>>>(stats, gn, bn, gc, bc, ab);

  cvt_k<<<(N_CSTR * DIM / 4 + 255) / 256, 256, 0, stream>>>((const float4*)cf, ab + 128,
                                                            xcb, N_CSTR * DIM / 4);
  cvt_k<<<(N_VAR * DIM / 4 + 255) / 256, 256, 0, stream>>>((const float4*)vf, ab,
                                                           xnb, N_VAR * DIM / 4);

  bhist_k<<<128, 256, 0, stream>>>((const int4*)es, (const int4*)ed, wsi);
  bscan_k<<<1, 256, 0, stream>>>(wsi);
  passA_k<<<2 * NCHUNK, 256, 0, stream>>>((const int4*)es, (const int4*)ed,
                                          (const float4*)ea, wsi);
  sort_k<<<NBK_T, 256, 0, stream>>>(wsi);

  gather_k<<<(N_VAR + 3) / 4, 256, 0, stream>>>(xcb_s, ent_n, wsi + OFF_OFF_N,
                                                agg_node, N_VAR);
  gather_k<<<(N_CSTR + 3) / 4, 256, 0, stream>>>(xnb_s, ent_c, wsi + OFF_OFF_C,
                                                 agg_cstr, N_CSTR);

  out_mfma_k<<<640, 256, 0, stream>>>(vf, ab, n_rel_w, n_rel_b, n_root_w,
                                      agg_node, N_VAR);
  out_mfma_k<<<320, 256, 0, stream>>>(cf, ab + 128, c_rel_w, c_rel_b, c_root_w,
                                      agg_cstr, N_CSTR);
}